// Round 1
// baseline (1967.246 us; speedup 1.0000x reference)
//
#include <hip/hip_runtime.h>
#include <math.h>

#define T_TOK 2048
#define H_DIM 1024
#define I_DIM 512
#define N_EXP 16
#define TOPK  4
#define NPAIR (T_TOK*TOPK)   /* 8192 */

// ---------- fp8 e4m3fn round-trip (RNE, value must already be in [-448,448]) ----------
__device__ __forceinline__ float fp8_rt(float v) {
    float av = fabsf(v);
    if (av < 0.015625f) {                 // e4m3 subnormal region: quantum 2^-9
        return rintf(v * 512.0f) * 0.001953125f;
    }
    unsigned u = __float_as_uint(v);
    unsigned lsb = (u >> 20) & 1u;        // keep 3 mantissa bits, RNE
    u = (u + 0x7FFFFu + lsb) & 0xFFF00000u;
    return __uint_as_float(u);
}

__device__ __forceinline__ float siluf(float x) {
    return x / (1.0f + expf(-x));
}

// ---------- K1: per-token, per-128-group quant-dequant of hidden_states ----------
// grid: T_TOK blocks x 256 threads. Each thread: 4 consecutive floats (float4).
// 32 consecutive lanes = one 128-element quant group.
__global__ void k_quant_x(const float* __restrict__ x, float* __restrict__ xq) {
    int t = blockIdx.x;
    int tid = threadIdx.x;
    const float4* xv = (const float4*)(x + (size_t)t * H_DIM);
    float4 v = xv[tid];
    float a = fmaxf(fmaxf(fabsf(v.x), fabsf(v.y)), fmaxf(fabsf(v.z), fabsf(v.w)));
    #pragma unroll
    for (int m = 16; m >= 1; m >>= 1) a = fmaxf(a, __shfl_xor(a, m));
    float s = fmaxf(a, 1e-10f) / 448.0f;
    float4 r;
    r.x = fp8_rt(fminf(fmaxf(v.x / s, -448.f), 448.f)) * s;
    r.y = fp8_rt(fminf(fmaxf(v.y / s, -448.f), 448.f)) * s;
    r.z = fp8_rt(fminf(fmaxf(v.z / s, -448.f), 448.f)) * s;
    r.w = fp8_rt(fminf(fmaxf(v.w / s, -448.f), 448.f)) * s;
    ((float4*)(xq + (size_t)t * H_DIM))[tid] = r;
}

// ---------- K2: routing lists ----------
__global__ void k_route(const int* __restrict__ idx, int* __restrict__ counts,
                        int* __restrict__ lists) {
    int p = blockIdx.x * 256 + threadIdx.x;
    if (p < NPAIR) {
        int e = idx[p];
        int pos = atomicAdd(&counts[e], 1);
        lists[e * NPAIR + pos] = p;
    }
}

// ---------- K3: gate_up GEMM + silu*up + re-quant ----------
// grid: (token_tile=256, i_tile=4, expert=16), 256 threads.
// Tile: 256 W-rows (gate rows it*128..+128 and up rows 512+it*128..+128) x 32 pairs, K=1024.
#define TT3 32
#define BK3 32
__global__ void k_gateup(const float* __restrict__ xq, const int* __restrict__ counts,
                         const int* __restrict__ lists, const float* __restrict__ wgu,
                         const float* __restrict__ sgu, float* __restrict__ hq) {
    int e = blockIdx.z, it = blockIdx.y, tt = blockIdx.x;
    int n = counts[e];
    if (tt * TT3 >= n) return;

    __shared__ float Wl[256][BK3 + 1];
    __shared__ float Xl[TT3][BK3 + 1];
    __shared__ int ptok[TT3];

    int tid = threadIdx.x;
    int to = tid & 63, tw = tid >> 6;
    if (tid < TT3) {
        int slot = tt * TT3 + tid;
        ptok[tid] = (slot < n) ? lists[e * NPAIR + slot] : -1;
    }
    __syncthreads();

    float acc[4][8] = {};   // rows o = to + i*64 (i<2: gate ii, i>=2: up ii), tokens tw*8+j
    const float* wbase = wgu + (size_t)e * (2 * I_DIM) * H_DIM;

    for (int kc = 0; kc < H_DIM; kc += BK3) {
        int kb = kc >> 7;
        float sg = sgu[((e * 8) + it) * 8 + kb];        // gate o-block = it
        float su = sgu[((e * 8) + 4 + it) * 8 + kb];    // up   o-block = 4+it
        #pragma unroll
        for (int l = 0; l < 32; ++l) {                  // 256x32 W elements
            int flat = l * 256 + tid;
            int lr = flat >> 5, lk = flat & 31;
            int og = (lr < 128) ? (it * 128 + lr) : (512 + it * 128 + (lr - 128));
            float s = (lr < 128) ? sg : su;
            Wl[lr][lk] = wbase[(size_t)og * H_DIM + kc + lk] * s;
        }
        #pragma unroll
        for (int l = 0; l < 4; ++l) {                   // 32x32 X elements
            int flat = l * 256 + tid;
            int ts = flat >> 5, lk = flat & 31;
            int p = ptok[ts];
            Xl[ts][lk] = (p >= 0) ? xq[(size_t)(p >> 2) * H_DIM + kc + lk] : 0.f;
        }
        __syncthreads();
        #pragma unroll 4
        for (int k = 0; k < BK3; ++k) {
            float w0 = Wl[to][k], w1 = Wl[to + 64][k];
            float w2 = Wl[to + 128][k], w3 = Wl[to + 192][k];
            float xv[8];
            #pragma unroll
            for (int j = 0; j < 8; ++j) xv[j] = Xl[tw * 8 + j][k];
            #pragma unroll
            for (int j = 0; j < 8; ++j) {
                acc[0][j] += w0 * xv[j];
                acc[1][j] += w1 * xv[j];
                acc[2][j] += w2 * xv[j];
                acc[3][j] += w3 * xv[j];
            }
        }
        __syncthreads();
    }

    // epilogue: h = silu(gate)*up ; quant per (pair, this 128-wide i-group)
    // thread holds gate[ii=to]=acc0, gate[ii=to+64]=acc1, up[ii=to]=acc2, up[ii=to+64]=acc3
    #pragma unroll
    for (int j = 0; j < 8; ++j) {
        int p = ptok[tw * 8 + j];
        float h0 = siluf(acc[0][j]) * acc[2][j];
        float h1 = siluf(acc[1][j]) * acc[3][j];
        float a = fmaxf(fabsf(h0), fabsf(h1));
        #pragma unroll
        for (int m = 32; m >= 1; m >>= 1) a = fmaxf(a, __shfl_xor(a, m));
        float s = fmaxf(a, 1e-10f) / 448.0f;
        float q0 = fp8_rt(fminf(fmaxf(h0 / s, -448.f), 448.f)) * s;
        float q1 = fp8_rt(fminf(fmaxf(h1 / s, -448.f), 448.f)) * s;
        if (p >= 0) {
            float* dst = hq + (size_t)p * I_DIM + it * 128;
            dst[to] = q0;
            dst[to + 64] = q1;
        }
    }
}

// ---------- K5: down GEMM + routing-weight scatter ----------
// grid: (token_tile=256, h_tile=8, expert=16), 256 threads.
// Tile: 128 W-rows x 32 pairs, K=512.
#define BK5 32
__global__ void k_down(const float* __restrict__ hq, const int* __restrict__ counts,
                       const int* __restrict__ lists, const float* __restrict__ wdn,
                       const float* __restrict__ sdn, const float* __restrict__ tkw,
                       float* __restrict__ out) {
    int e = blockIdx.z, hb = blockIdx.y, tt = blockIdx.x;
    int n = counts[e];
    if (tt * TT3 >= n) return;

    __shared__ float Wl[128][BK5 + 1];
    __shared__ float Xl[TT3][BK5 + 1];
    __shared__ int ptok[TT3];

    int tid = threadIdx.x;
    int to = tid & 63, tw = tid >> 6;
    if (tid < TT3) {
        int slot = tt * TT3 + tid;
        ptok[tid] = (slot < n) ? lists[e * NPAIR + slot] : -1;
    }
    __syncthreads();

    float acc[2][8] = {};
    const float* wbase = wdn + (size_t)e * H_DIM * I_DIM;

    for (int kc = 0; kc < I_DIM; kc += BK5) {
        float sv = sdn[(e * 8 + hb) * 4 + (kc >> 7)];
        #pragma unroll
        for (int l = 0; l < 16; ++l) {                  // 128x32 W elements
            int flat = l * 256 + tid;
            int lr = flat >> 5, lk = flat & 31;
            Wl[lr][lk] = wbase[(size_t)(hb * 128 + lr) * I_DIM + kc + lk] * sv;
        }
        #pragma unroll
        for (int l = 0; l < 4; ++l) {
            int flat = l * 256 + tid;
            int ts = flat >> 5, lk = flat & 31;
            int p = ptok[ts];
            Xl[ts][lk] = (p >= 0) ? hq[(size_t)p * I_DIM + kc + lk] : 0.f;
        }
        __syncthreads();
        #pragma unroll 4
        for (int k = 0; k < BK5; ++k) {
            float w0 = Wl[to][k], w1 = Wl[to + 64][k];
            #pragma unroll
            for (int j = 0; j < 8; ++j) {
                float xv = Xl[tw * 8 + j][k];
                acc[0][j] += w0 * xv;
                acc[1][j] += w1 * xv;
            }
        }
        __syncthreads();
    }

    #pragma unroll
    for (int j = 0; j < 8; ++j) {
        int p = ptok[tw * 8 + j];
        if (p < 0) continue;
        int t = p >> 2, ks = p & 3;
        float w = tkw[t * TOPK + ks];
        atomicAdd(&out[(size_t)t * H_DIM + hb * 128 + to],      w * acc[0][j]);
        atomicAdd(&out[(size_t)t * H_DIM + hb * 128 + to + 64], w * acc[1][j]);
    }
}

extern "C" void kernel_launch(void* const* d_in, const int* in_sizes, int n_in,
                              void* d_out, int out_size, void* d_ws, size_t ws_size,
                              hipStream_t stream) {
    const float* hs  = (const float*)d_in[0];
    const int*   tki = (const int*)d_in[1];
    const float* tkw = (const float*)d_in[2];
    const float* wgu = (const float*)d_in[3];
    const float* sgu = (const float*)d_in[4];
    const float* wdn = (const float*)d_in[5];
    const float* sdn = (const float*)d_in[6];
    float* out = (float*)d_out;

    char* ws = (char*)d_ws;
    float* xq   = (float*)ws;                              // T*H f32   = 8 MB
    float* hq   = (float*)(ws + (size_t)8 * 1024 * 1024);  // NPAIR*I   = 16 MB
    int* counts = (int*)(ws + (size_t)24 * 1024 * 1024);   // E ints
    int* lists  = counts + 64;                             // E*NPAIR ints = 512 KB

    hipMemsetAsync(out, 0, (size_t)T_TOK * H_DIM * sizeof(float), stream);
    hipMemsetAsync(counts, 0, N_EXP * sizeof(int), stream);

    k_quant_x<<<T_TOK, 256, 0, stream>>>(hs, xq);
    k_route<<<NPAIR / 256, 256, 0, stream>>>(tki, counts, lists);
    k_gateup<<<dim3(NPAIR / TT3, 4, N_EXP), 256, 0, stream>>>(xq, counts, lists, wgu, sgu, hq);
    k_down<<<dim3(NPAIR / TT3, 8, N_EXP), 256, 0, stream>>>(hq, counts, lists, wdn, sdn, tkw, out);
}

// Round 2
// 536.213 us; speedup vs baseline: 3.6688x; 3.6688x over previous
//
#include <hip/hip_runtime.h>
#include <math.h>

#define T_TOK 2048
#define H_DIM 1024
#define I_DIM 512
#define N_EXP 16
#define TOPK  4
#define NPAIR (T_TOK*TOPK)   /* 8192 */

typedef unsigned short u16;
typedef __attribute__((ext_vector_type(8))) short s8v;   // 8 bf16 codes (4 VGPR)
typedef __attribute__((ext_vector_type(4))) float f4v;   // MFMA accumulator

#define GLDS(g, l) __builtin_amdgcn_global_load_lds( \
    (const __attribute__((address_space(1))) void*)(g), \
    (__attribute__((address_space(3))) void*)(l), 16, 0, 0)

// ---------- fp8 e4m3fn round-trip (RNE); input must be in [-448,448] ----------
__device__ __forceinline__ float fp8_rt(float v) {
    float av = fabsf(v);
    if (av < 0.015625f) {                 // subnormal region: quantum 2^-9
        return rintf(v * 512.0f) * 0.001953125f;
    }
    unsigned u = __float_as_uint(v);
    unsigned lsb = (u >> 20) & 1u;        // keep 3 mantissa bits, RNE
    u = (u + 0x7FFFFu + lsb) & 0xFFF00000u;
    return __uint_as_float(u);
}

__device__ __forceinline__ u16 f2bf(float v) {   // exact for fp8-representable values
    return (u16)(__float_as_uint(v) >> 16);
}

// ---------- K0: f32 -> bf16 code conversion (exact) ----------
__global__ void k_cvt(const float* __restrict__ in, u16* __restrict__ out, int n8) {
    int i = blockIdx.x * 256 + threadIdx.x;   // 8 elements per thread
    if (i >= n8) return;
    const float4* p = (const float4*)in + (size_t)i * 2;
    float4 a = p[0], b = p[1];
    int4 st;
    st.x = (int)((unsigned)f2bf(a.x) | ((unsigned)f2bf(a.y) << 16));
    st.y = (int)((unsigned)f2bf(a.z) | ((unsigned)f2bf(a.w) << 16));
    st.z = (int)((unsigned)f2bf(b.x) | ((unsigned)f2bf(b.y) << 16));
    st.w = (int)((unsigned)f2bf(b.z) | ((unsigned)f2bf(b.w) << 16));
    ((int4*)out)[i] = st;
}

// ---------- K1: x -> fp8 codes (bf16) + per-128-group scales ----------
__global__ void k_quant_x(const float* __restrict__ x, u16* __restrict__ xq,
                          float* __restrict__ xs) {
    int t = blockIdx.x, tid = threadIdx.x;
    float4 v = ((const float4*)(x + (size_t)t * H_DIM))[tid];
    float a = fmaxf(fmaxf(fabsf(v.x), fabsf(v.y)), fmaxf(fabsf(v.z), fabsf(v.w)));
    #pragma unroll
    for (int m = 16; m >= 1; m >>= 1) a = fmaxf(a, __shfl_xor(a, m));
    float s = fmaxf(a, 1e-10f) / 448.0f;
    ushort4 r;
    r.x = f2bf(fp8_rt(fminf(fmaxf(v.x / s, -448.f), 448.f)));
    r.y = f2bf(fp8_rt(fminf(fmaxf(v.y / s, -448.f), 448.f)));
    r.z = f2bf(fp8_rt(fminf(fmaxf(v.z / s, -448.f), 448.f)));
    r.w = f2bf(fp8_rt(fminf(fmaxf(v.w / s, -448.f), 448.f)));
    ((ushort4*)(xq + (size_t)t * H_DIM))[tid] = r;
    if ((tid & 31) == 0) xs[t * 8 + (tid >> 5)] = s;
}

// ---------- K2: routing lists ----------
__global__ void k_route(const int* __restrict__ idx, int* __restrict__ counts,
                        int* __restrict__ lists) {
    int p = blockIdx.x * 256 + threadIdx.x;
    if (p < NPAIR) {
        int e = idx[p];
        int pos = atomicAdd(&counts[e], 1);
        lists[e * NPAIR + pos] = p;
    }
}

// ---------- K3: gate_up MFMA GEMM + silu*up + re-quant ----------
// grid (tt=128, it=4, e=16) x 512 thr. Block tile: M=64 pairs x N=256 (gate128|up128), BK=128.
// 8 waves: m = w&1 (row half), q = w>>1 (32-col slice of the 128-i group).
__global__ void k_gateup(const u16* __restrict__ xq, const float* __restrict__ xs,
                         const int* __restrict__ counts, const int* __restrict__ lists,
                         const u16* __restrict__ wgu, const float* __restrict__ sgu,
                         const u16* __restrict__ zbuf,
                         u16* __restrict__ hq, float* __restrict__ hs) {
    int e = blockIdx.z, it = blockIdx.y, tt = blockIdx.x;
    int n = counts[e];
    if (tt * 64 >= n) return;

    __shared__ __align__(16) u16 Bsh[256 * 128];   // 64 KB, XOR-swizzled 16B slots
    __shared__ float xs_l[64][8];
    __shared__ int ptok[64];

    int tid = threadIdx.x;
    int w = tid >> 6, lane = tid & 63;
    int m = w & 1, q = w >> 1;
    int l15 = lane & 15, l4 = lane >> 4;

    if (tid < 64) {
        int slot = tt * 64 + tid;
        ptok[tid] = (slot < n) ? lists[e * NPAIR + slot] : -1;
    }
    __syncthreads();
    {
        int row = tid >> 3, kb = tid & 7;
        int p = ptok[row];
        xs_l[row][kb] = (p >= 0) ? xs[(p >> 2) * 8 + kb] : 0.f;
    }

    int lr0 = m * 32 + l15, lr1 = lr0 + 16;
    int p0 = ptok[lr0], p1 = ptok[lr1];
    const u16* aptr0 = (p0 >= 0) ? xq + (size_t)(p0 >> 2) * H_DIM : zbuf;
    const u16* aptr1 = (p1 >= 0) ? xq + (size_t)(p1 >> 2) * H_DIM : zbuf;
    const u16* wbase = wgu + (size_t)e * (2 * I_DIM) * H_DIM;
    const float* sgu_e = sgu + e * 64;

    f4v master[2][4];
    #pragma unroll
    for (int a = 0; a < 2; ++a)
        #pragma unroll
        for (int b = 0; b < 4; ++b) master[a][b] = (f4v){0.f, 0.f, 0.f, 0.f};

    for (int kc = 0; kc < 8; ++kc) {
        #pragma unroll
        for (int i = 0; i < 8; ++i) {               // stage B: 256 rows x 128 k bf16
            int s = i * 512 + tid;
            int row = s >> 4, c = s & 15;
            int cg = c ^ (row & 7);                  // pre-swizzled source (T2/m173)
            int wrow = (row < 128) ? (it * 128 + row) : (384 + it * 128 + row);
            const u16* src = wbase + (size_t)wrow * H_DIM + kc * 128 + cg * 8;
            GLDS(src, &Bsh[s * 8]);
        }
        __syncthreads();

        f4v part[2][4];
        #pragma unroll
        for (int a = 0; a < 2; ++a)
            #pragma unroll
            for (int b = 0; b < 4; ++b) part[a][b] = (f4v){0.f, 0.f, 0.f, 0.f};

        #pragma unroll
        for (int kg = 0; kg < 4; ++kg) {
            int ko = kc * 128 + kg * 32 + l4 * 8;
            s8v a0 = *(const s8v*)(aptr0 + ko);
            s8v a1 = *(const s8v*)(aptr1 + ko);
            #pragma unroll
            for (int nf = 0; nf < 4; ++nf) {
                int brow = q * 32 + (nf & 1) * 16 + (nf >> 1) * 128 + l15;
                int slot = (brow << 4) + ((kg * 4 + l4) ^ (brow & 7));
                s8v b = *(const s8v*)&Bsh[slot * 8];
                part[0][nf] = __builtin_amdgcn_mfma_f32_16x16x32_bf16(a0, b, part[0][nf], 0, 0, 0);
                part[1][nf] = __builtin_amdgcn_mfma_f32_16x16x32_bf16(a1, b, part[1][nf], 0, 0, 0);
            }
        }
        float swg = sgu_e[it * 8 + kc];
        float swu = sgu_e[(4 + it) * 8 + kc];
        #pragma unroll
        for (int fm = 0; fm < 2; ++fm) {
            #pragma unroll
            for (int r = 0; r < 4; ++r) {
                float sx = xs_l[m * 32 + fm * 16 + l4 * 4 + r][kc];
                float sg2 = sx * swg, su2 = sx * swu;
                master[fm][0][r] += part[fm][0][r] * sg2;
                master[fm][1][r] += part[fm][1][r] * sg2;
                master[fm][2][r] += part[fm][2][r] * su2;
                master[fm][3][r] += part[fm][3][r] * su2;
            }
        }
        __syncthreads();
    }

    // epilogue: h = silu(gate)*up -> LDS (reuse B) -> per-row quant over the 128-i group
    float* Hl = (float*)Bsh;   // [64][128] f32
    #pragma unroll
    for (int fm = 0; fm < 2; ++fm)
        #pragma unroll
        for (int j = 0; j < 2; ++j)
            #pragma unroll
            for (int r = 0; r < 4; ++r) {
                float g = master[fm][j][r], u = master[fm][2 + j][r];
                float h = (g / (1.0f + expf(-g))) * u;
                Hl[(m * 32 + fm * 16 + l4 * 4 + r) * 128 + q * 32 + j * 16 + l15] = h;
            }
    __syncthreads();
    {
        int row = tid >> 3, sl = tid & 7;
        int p = ptok[row];
        float hv[16];
        float vmax = 0.f;
        #pragma unroll
        for (int c = 0; c < 16; ++c) {
            hv[c] = Hl[row * 128 + sl * 16 + c];
            vmax = fmaxf(vmax, fabsf(hv[c]));
        }
        #pragma unroll
        for (int msk = 4; msk >= 1; msk >>= 1) vmax = fmaxf(vmax, __shfl_xor(vmax, msk));
        float s = fmaxf(vmax, 1e-10f) / 448.0f;
        if (p >= 0) {
            u16 qc[16];
            #pragma unroll
            for (int c = 0; c < 16; ++c) {
                float z = fminf(fmaxf(hv[c] / s, -448.f), 448.f);
                qc[c] = f2bf(fp8_rt(z));
            }
            u16* dst = hq + (size_t)p * I_DIM + it * 128 + sl * 16;
            int4 s0, s1;
            s0.x = qc[0] | (qc[1] << 16);  s0.y = qc[2] | (qc[3] << 16);
            s0.z = qc[4] | (qc[5] << 16);  s0.w = qc[6] | (qc[7] << 16);
            s1.x = qc[8] | (qc[9] << 16);  s1.y = qc[10] | (qc[11] << 16);
            s1.z = qc[12] | (qc[13] << 16); s1.w = qc[14] | (qc[15] << 16);
            ((int4*)dst)[0] = s0;
            ((int4*)dst)[1] = s1;
            if (sl == 0) hs[p * 4 + it] = s;
        }
    }
}

// ---------- K4: down MFMA GEMM + routing-weight scatter ----------
// grid (tt=128, hb=4, e=16) x 512 thr. Block tile: M=64 x N=256 (contig o), BK=128, K=512.
__global__ void k_down(const u16* __restrict__ hq, const float* __restrict__ hs,
                       const int* __restrict__ counts, const int* __restrict__ lists,
                       const u16* __restrict__ wdn, const float* __restrict__ sdn,
                       const float* __restrict__ tkw, const u16* __restrict__ zbuf,
                       float* __restrict__ out) {
    int e = blockIdx.z, hb = blockIdx.y, tt = blockIdx.x;
    int n = counts[e];
    if (tt * 64 >= n) return;

    __shared__ __align__(16) u16 Bsh[256 * 128];
    __shared__ float hs_l[64][4];
    __shared__ float rw_l[64];
    __shared__ int ptok[64];

    int tid = threadIdx.x;
    int w = tid >> 6, lane = tid & 63;
    int m = w & 1, q = w >> 1;
    int l15 = lane & 15, l4 = lane >> 4;

    if (tid < 64) {
        int slot = tt * 64 + tid;
        ptok[tid] = (slot < n) ? lists[e * NPAIR + slot] : -1;
    }
    __syncthreads();
    if (tid < 256) {
        int row = tid >> 2, kb = tid & 3;
        int p = ptok[row];
        hs_l[row][kb] = (p >= 0) ? hs[p * 4 + kb] : 0.f;
    } else if (tid < 320) {
        int row = tid - 256;
        int p = ptok[row];
        rw_l[row] = (p >= 0) ? tkw[p] : 0.f;
    }

    int lr0 = m * 32 + l15, lr1 = lr0 + 16;
    int p0 = ptok[lr0], p1 = ptok[lr1];
    const u16* aptr0 = (p0 >= 0) ? hq + (size_t)p0 * I_DIM : zbuf;
    const u16* aptr1 = (p1 >= 0) ? hq + (size_t)p1 * I_DIM : zbuf;
    const u16* wbase = wdn + (size_t)e * H_DIM * I_DIM + (size_t)hb * 256 * I_DIM;

    f4v master[2][4];
    #pragma unroll
    for (int a = 0; a < 2; ++a)
        #pragma unroll
        for (int b = 0; b < 4; ++b) master[a][b] = (f4v){0.f, 0.f, 0.f, 0.f};

    for (int kc = 0; kc < 4; ++kc) {
        #pragma unroll
        for (int i = 0; i < 8; ++i) {
            int s = i * 512 + tid;
            int row = s >> 4, c = s & 15;
            int cg = c ^ (row & 7);
            const u16* src = wbase + (size_t)row * I_DIM + kc * 128 + cg * 8;
            GLDS(src, &Bsh[s * 8]);
        }
        __syncthreads();

        f4v part[2][4];
        #pragma unroll
        for (int a = 0; a < 2; ++a)
            #pragma unroll
            for (int b = 0; b < 4; ++b) part[a][b] = (f4v){0.f, 0.f, 0.f, 0.f};

        #pragma unroll
        for (int kg = 0; kg < 4; ++kg) {
            int ko = kc * 128 + kg * 32 + l4 * 8;
            s8v a0 = *(const s8v*)(aptr0 + ko);
            s8v a1 = *(const s8v*)(aptr1 + ko);
            #pragma unroll
            for (int nf = 0; nf < 4; ++nf) {
                int brow = q * 64 + nf * 16 + l15;
                int slot = (brow << 4) + ((kg * 4 + l4) ^ (brow & 7));
                s8v b = *(const s8v*)&Bsh[slot * 8];
                part[0][nf] = __builtin_amdgcn_mfma_f32_16x16x32_bf16(a0, b, part[0][nf], 0, 0, 0);
                part[1][nf] = __builtin_amdgcn_mfma_f32_16x16x32_bf16(a1, b, part[1][nf], 0, 0, 0);
            }
        }
        float sw = sdn[(e * 8 + hb * 2 + (q >> 1)) * 4 + kc];
        #pragma unroll
        for (int fm = 0; fm < 2; ++fm) {
            #pragma unroll
            for (int r = 0; r < 4; ++r) {
                float sx = hs_l[m * 32 + fm * 16 + l4 * 4 + r][kc] * sw;
                #pragma unroll
                for (int nf = 0; nf < 4; ++nf)
                    master[fm][nf][r] += part[fm][nf][r] * sx;
            }
        }
        __syncthreads();
    }

    #pragma unroll
    for (int fm = 0; fm < 2; ++fm)
        #pragma unroll
        for (int r = 0; r < 4; ++r) {
            int row = m * 32 + fm * 16 + l4 * 4 + r;
            int p = ptok[row];
            if (p < 0) continue;
            float rw = rw_l[row];
            float* orow = out + (size_t)(p >> 2) * H_DIM + hb * 256 + q * 64 + l15;
            #pragma unroll
            for (int nf = 0; nf < 4; ++nf)
                atomicAdd(orow + nf * 16, rw * master[fm][nf][r]);
        }
}

extern "C" void kernel_launch(void* const* d_in, const int* in_sizes, int n_in,
                              void* d_out, int out_size, void* d_ws, size_t ws_size,
                              hipStream_t stream) {
    const float* hs_in = (const float*)d_in[0];
    const int*   tki = (const int*)d_in[1];
    const float* tkw = (const float*)d_in[2];
    const float* wgu = (const float*)d_in[3];
    const float* sgu = (const float*)d_in[4];
    const float* wdn = (const float*)d_in[5];
    const float* sdn = (const float*)d_in[6];
    float* out = (float*)d_out;

    char* ws = (char*)d_ws;
    const size_t MB = 1024 * 1024;
    u16*   wgu_bf = (u16*)(ws);                    // 32 MB  (E*2I*H bf16)
    u16*   wdn_bf = (u16*)(ws + 32 * MB);          // 16 MB  (E*H*I bf16)
    u16*   xq     = (u16*)(ws + 48 * MB);          // 4 MB   (T*H bf16 codes)
    float* xs     = (float*)(ws + 52 * MB);        // 64 KB  (T*8)
    u16*   hq     = (u16*)(ws + 53 * MB);          // 8 MB   (NPAIR*I bf16 codes)
    float* hs     = (float*)(ws + 61 * MB);        // 128 KB (NPAIR*4)
    int*   counts = (int*)(ws + 62 * MB);          // 64 ints
    int*   lists  = (int*)(ws + 62 * MB + 4096);   // 512 KB
    u16*   zbuf   = (u16*)(ws + 63 * MB);          // 4 KB zeros

    hipMemsetAsync(out, 0, (size_t)T_TOK * H_DIM * sizeof(float), stream);
    hipMemsetAsync(counts, 0, 256, stream);
    hipMemsetAsync(zbuf, 0, 4096, stream);

    k_cvt<<<8192, 256, 0, stream>>>(wgu, wgu_bf, N_EXP * 2 * I_DIM * H_DIM / 8);
    k_cvt<<<4096, 256, 0, stream>>>(wdn, wdn_bf, N_EXP * H_DIM * I_DIM / 8);
    k_quant_x<<<T_TOK, 256, 0, stream>>>(hs_in, xq, xs);
    k_route<<<NPAIR / 256, 256, 0, stream>>>(tki, counts, lists);
    k_gateup<<<dim3(128, 4, N_EXP), 512, 0, stream>>>(xq, xs, counts, lists,
                                                      wgu_bf, sgu, zbuf, hq, hs);
    k_down<<<dim3(128, 4, N_EXP), 512, 0, stream>>>(hq, hs, counts, lists,
                                                    wdn_bf, sdn, tkw, zbuf, out);
}

// Round 3
// 255.392 us; speedup vs baseline: 7.7029x; 2.0996x over previous
//
#include <hip/hip_runtime.h>
#include <math.h>

#define T_TOK 2048
#define H_DIM 1024
#define I_DIM 512
#define N_EXP 16
#define TOPK  4
#define NPAIR (T_TOK*TOPK)   /* 8192 */

typedef unsigned short u16;
typedef __attribute__((ext_vector_type(8))) short s8v;   // 8 bf16 codes (4 VGPR)
typedef __attribute__((ext_vector_type(4))) float f4v;   // MFMA accumulator

#define GLDS(g, l) __builtin_amdgcn_global_load_lds( \
    (const __attribute__((address_space(1))) void*)(g), \
    (__attribute__((address_space(3))) void*)(l), 16, 0, 0)

// ---------- fp8 e4m3fn round-trip (RNE); input must be in [-448,448] ----------
__device__ __forceinline__ float fp8_rt(float v) {
    float av = fabsf(v);
    if (av < 0.015625f) {                 // subnormal region: quantum 2^-9
        return rintf(v * 512.0f) * 0.001953125f;
    }
    unsigned u = __float_as_uint(v);
    unsigned lsb = (u >> 20) & 1u;        // keep 3 mantissa bits, RNE
    u = (u + 0x7FFFFu + lsb) & 0xFFF00000u;
    return __uint_as_float(u);
}

__device__ __forceinline__ u16 f2bf(float v) {   // exact for fp8-representable values
    return (u16)(__float_as_uint(v) >> 16);
}

// ---------- K0: f32 -> bf16 code conversion (exact) ----------
__global__ void k_cvt(const float* __restrict__ in, u16* __restrict__ out, int n8) {
    int i = blockIdx.x * 256 + threadIdx.x;   // 8 elements per thread
    if (i >= n8) return;
    const float4* p = (const float4*)in + (size_t)i * 2;
    float4 a = p[0], b = p[1];
    int4 st;
    st.x = (int)((unsigned)f2bf(a.x) | ((unsigned)f2bf(a.y) << 16));
    st.y = (int)((unsigned)f2bf(a.z) | ((unsigned)f2bf(a.w) << 16));
    st.z = (int)((unsigned)f2bf(b.x) | ((unsigned)f2bf(b.y) << 16));
    st.w = (int)((unsigned)f2bf(b.z) | ((unsigned)f2bf(b.w) << 16));
    ((int4*)out)[i] = st;
}

// ---------- K1: x -> fp8 codes (bf16) + per-128-group scales ----------
__global__ void k_quant_x(const float* __restrict__ x, u16* __restrict__ xq,
                          float* __restrict__ xs) {
    int t = blockIdx.x, tid = threadIdx.x;
    float4 v = ((const float4*)(x + (size_t)t * H_DIM))[tid];
    float a = fmaxf(fmaxf(fabsf(v.x), fabsf(v.y)), fmaxf(fabsf(v.z), fabsf(v.w)));
    #pragma unroll
    for (int m = 16; m >= 1; m >>= 1) a = fmaxf(a, __shfl_xor(a, m));
    float s = fmaxf(a, 1e-10f) / 448.0f;
    ushort4 r;
    r.x = f2bf(fp8_rt(fminf(fmaxf(v.x / s, -448.f), 448.f)));
    r.y = f2bf(fp8_rt(fminf(fmaxf(v.y / s, -448.f), 448.f)));
    r.z = f2bf(fp8_rt(fminf(fmaxf(v.z / s, -448.f), 448.f)));
    r.w = f2bf(fp8_rt(fminf(fmaxf(v.w / s, -448.f), 448.f)));
    ((ushort4*)(xq + (size_t)t * H_DIM))[tid] = r;
    if ((tid & 31) == 0) xs[t * 8 + (tid >> 5)] = s;
}

// ---------- K2: routing lists ----------
__global__ void k_route(const int* __restrict__ idx, int* __restrict__ counts,
                        int* __restrict__ lists) {
    int p = blockIdx.x * 256 + threadIdx.x;
    if (p < NPAIR) {
        int e = idx[p];
        int pos = atomicAdd(&counts[e], 1);
        lists[e * NPAIR + pos] = p;
    }
}

// ---------- K3: gate_up MFMA GEMM (2-phase pipelined) ----------
// grid 2048 1-D: e = bid&15 (XCD pin), tile = bid>>4: tt = tile>>3 (M-tile of 64 pairs),
// it = tile&7 (64 gate cols [it*64,+64) + 64 up cols [512+it*64,+64)).
// 256 thr = 4 waves (m = w&1 row-half, q = w>>1: 0=gate cols, 1=up cols), wave-tile 32x64.
// K=1024, BK=64 (16 chunks), fold scales every 2 chunks (kb = t>>1).
__global__ __launch_bounds__(256, 3)
void k_gateup(const u16* __restrict__ xq, const float* __restrict__ xs,
              const int* __restrict__ counts, const int* __restrict__ lists,
              const u16* __restrict__ wgu, const float* __restrict__ sgu,
              const u16* __restrict__ zbuf, float* __restrict__ hbuf) {
    int bid = blockIdx.x;
    int e = bid & 15, tile = bid >> 4;
    int tt = tile >> 3, it = tile & 7;
    int n = counts[e];
    if (tt * 64 >= n) return;

    __shared__ __align__(16) u16 sm[2][12288];   // per buf: B 1024 slots | A 512 slots (24 KB)
    __shared__ float xs_l[64][8];
    __shared__ int ptok[64];

    int tid = threadIdx.x;
    int w = tid >> 6, lane = tid & 63;
    int m = w & 1, q = w >> 1;
    int l15 = lane & 15, l4 = lane >> 4;

    if (tid < 64) {
        int slot = tt * 64 + tid;
        ptok[tid] = (slot < n) ? lists[e * NPAIR + slot] : -1;
    }
    __syncthreads();
    {
        int r = tid >> 2, kb4 = (tid & 3) * 2;
        int p = ptok[r];
        xs_l[r][kb4]     = (p >= 0) ? xs[(p >> 2) * 8 + kb4]     : 0.f;
        xs_l[r][kb4 + 1] = (p >= 0) ? xs[(p >> 2) * 8 + kb4 + 1] : 0.f;
    }

    // stage-source precompute (pre-swizzled global addresses; LDS dest stays linear)
    const u16* wbase = wgu + (size_t)e * 1024 * 1024;
    const u16* srcB[4];
    #pragma unroll
    for (int j = 0; j < 4; ++j) {
        int s = j * 256 + tid;
        int row = s >> 3, c = s & 7, cg = c ^ (row & 7);
        int nrow = (row < 64) ? it * 64 + row : 448 + it * 64 + row;  // gate | up
        srcB[j] = wbase + (size_t)nrow * H_DIM + cg * 8;
    }
    const u16* srcA[2];
    #pragma unroll
    for (int j = 0; j < 2; ++j) {
        int s = j * 256 + tid;
        int row = s >> 3, c = s & 7, cg = c ^ (row & 7);
        int p = ptok[row];
        srcA[j] = (p >= 0) ? xq + (size_t)(p >> 2) * H_DIM + cg * 8 : zbuf;
    }

    // fragment LDS read offsets (u16 units; row stride 64 u16 = 128B, XOR swizzle)
    int idxA[2][2], idxB[4][2];
    #pragma unroll
    for (int fm = 0; fm < 2; ++fm) {
        int ar = m * 32 + fm * 16 + l15;
        #pragma unroll
        for (int kg = 0; kg < 2; ++kg)
            idxA[fm][kg] = 8192 + ar * 64 + (((kg * 4 + l4) ^ (ar & 7)) * 8);
    }
    #pragma unroll
    for (int nf = 0; nf < 4; ++nf) {
        int br = q * 64 + nf * 16 + l15;
        #pragma unroll
        for (int kg = 0; kg < 2; ++kg)
            idxB[nf][kg] = br * 64 + (((kg * 4 + l4) ^ (br & 7)) * 8);
    }

    auto stage = [&](int buf) {
        #pragma unroll
        for (int j = 0; j < 4; ++j) { GLDS(srcB[j], &sm[buf][j * 2048 + tid * 8]); srcB[j] += 64; }
        #pragma unroll
        for (int j = 0; j < 2; ++j) { GLDS(srcA[j], &sm[buf][8192 + j * 2048 + tid * 8]); srcA[j] += 64; }
    };

    f4v master[2][4], part[2][4];
    #pragma unroll
    for (int a = 0; a < 2; ++a)
        #pragma unroll
        for (int b = 0; b < 4; ++b) { master[a][b] = (f4v){0,0,0,0}; part[a][b] = (f4v){0,0,0,0}; }

    const float* swp = sgu + e * 64 + (q ? 4 + (it >> 1) : (it >> 1)) * 8;

    stage(0);
    __syncthreads();

    for (int t = 0; t < 16; ++t) {
        if (t < 15) stage((t + 1) & 1);
        const u16* buf = &sm[t & 1][0];
        #pragma unroll
        for (int kg = 0; kg < 2; ++kg) {
            s8v a0 = *(const s8v*)&buf[idxA[0][kg]];
            s8v a1 = *(const s8v*)&buf[idxA[1][kg]];
            #pragma unroll
            for (int nf = 0; nf < 4; ++nf) {
                s8v b = *(const s8v*)&buf[idxB[nf][kg]];
                part[0][nf] = __builtin_amdgcn_mfma_f32_16x16x32_bf16(a0, b, part[0][nf], 0, 0, 0);
                part[1][nf] = __builtin_amdgcn_mfma_f32_16x16x32_bf16(a1, b, part[1][nf], 0, 0, 0);
            }
        }
        if (t & 1) {
            int kb = t >> 1;
            float sw = swp[kb];
            #pragma unroll
            for (int fm = 0; fm < 2; ++fm) {
                float c0 = xs_l[m * 32 + fm * 16 + l4 * 4 + 0][kb] * sw;
                float c1 = xs_l[m * 32 + fm * 16 + l4 * 4 + 1][kb] * sw;
                float c2 = xs_l[m * 32 + fm * 16 + l4 * 4 + 2][kb] * sw;
                float c3 = xs_l[m * 32 + fm * 16 + l4 * 4 + 3][kb] * sw;
                #pragma unroll
                for (int nf = 0; nf < 4; ++nf) {
                    master[fm][nf][0] += c0 * part[fm][nf][0];
                    master[fm][nf][1] += c1 * part[fm][nf][1];
                    master[fm][nf][2] += c2 * part[fm][nf][2];
                    master[fm][nf][3] += c3 * part[fm][nf][3];
                    part[fm][nf] = (f4v){0,0,0,0};
                }
            }
        }
        __syncthreads();
    }

    // epilogue: q=1 waves park up in LDS; q=0 waves fuse silu(gate)*up -> hbuf f32
    float* Ul = (float*)sm;   // [64][65]
    if (q == 1) {
        #pragma unroll
        for (int fm = 0; fm < 2; ++fm)
            #pragma unroll
            for (int nf = 0; nf < 4; ++nf)
                #pragma unroll
                for (int r = 0; r < 4; ++r)
                    Ul[(m * 32 + fm * 16 + l4 * 4 + r) * 65 + nf * 16 + l15] = master[fm][nf][r];
    }
    __syncthreads();
    if (q == 0) {
        #pragma unroll
        for (int fm = 0; fm < 2; ++fm)
            #pragma unroll
            for (int r = 0; r < 4; ++r) {
                int row = m * 32 + fm * 16 + l4 * 4 + r;
                int p = ptok[row];
                if (p < 0) continue;
                float* drow = hbuf + (size_t)p * I_DIM + it * 64;
                #pragma unroll
                for (int nf = 0; nf < 4; ++nf) {
                    float g = master[fm][nf][r];
                    float u = Ul[row * 65 + nf * 16 + l15];
                    drow[nf * 16 + l15] = (g / (1.0f + expf(-g))) * u;
                }
            }
    }
}

// ---------- K4: h -> fp8 codes (bf16) + per-128-group scales ----------
__global__ void k_quant_h(const float* __restrict__ h, u16* __restrict__ hq,
                          float* __restrict__ hs) {
    int p = blockIdx.x, tid = threadIdx.x;   // 128 threads, 4 f32 each
    float4 v = ((const float4*)(h + (size_t)p * I_DIM))[tid];
    float a = fmaxf(fmaxf(fabsf(v.x), fabsf(v.y)), fmaxf(fabsf(v.z), fabsf(v.w)));
    #pragma unroll
    for (int m = 16; m >= 1; m >>= 1) a = fmaxf(a, __shfl_xor(a, m));
    float s = fmaxf(a, 1e-10f) / 448.0f;
    ushort4 r;
    r.x = f2bf(fp8_rt(fminf(fmaxf(v.x / s, -448.f), 448.f)));
    r.y = f2bf(fp8_rt(fminf(fmaxf(v.y / s, -448.f), 448.f)));
    r.z = f2bf(fp8_rt(fminf(fmaxf(v.z / s, -448.f), 448.f)));
    r.w = f2bf(fp8_rt(fminf(fmaxf(v.w / s, -448.f), 448.f)));
    ((ushort4*)(hq + (size_t)p * I_DIM))[tid] = r;
    if ((tid & 31) == 0) hs[p * 4 + (tid >> 5)] = s;
}

// ---------- K5: down MFMA GEMM (2-phase pipelined) + rw-weighted partial write ----------
// grid 2048: e = bid&15, tile = bid>>4: tt = tile>>3, nt = tile&7 (128 H-cols).
// K=512, BK=64 (8 chunks), fold every 2 (kb = t>>1, 4 scale blocks).
__global__ __launch_bounds__(256, 3)
void k_down(const u16* __restrict__ hq, const float* __restrict__ hs,
            const int* __restrict__ counts, const int* __restrict__ lists,
            const u16* __restrict__ wdn, const float* __restrict__ sdn,
            const float* __restrict__ tkw, const u16* __restrict__ zbuf,
            float* __restrict__ dout) {
    int bid = blockIdx.x;
    int e = bid & 15, tile = bid >> 4;
    int tt = tile >> 3, nt = tile & 7;
    int n = counts[e];
    if (tt * 64 >= n) return;

    __shared__ __align__(16) u16 sm[2][12288];
    __shared__ float hs_l[64][4];
    __shared__ float rw_l[64];
    __shared__ int ptok[64];

    int tid = threadIdx.x;
    int w = tid >> 6, lane = tid & 63;
    int m = w & 1, q = w >> 1;
    int l15 = lane & 15, l4 = lane >> 4;

    if (tid < 64) {
        int slot = tt * 64 + tid;
        ptok[tid] = (slot < n) ? lists[e * NPAIR + slot] : -1;
    }
    __syncthreads();
    {
        int r = tid >> 2, kb = tid & 3;
        int p = ptok[r];
        hs_l[r][kb] = (p >= 0) ? hs[p * 4 + kb] : 0.f;
        if (tid < 64) rw_l[tid] = (ptok[tid] >= 0) ? tkw[ptok[tid]] : 0.f;
    }

    const u16* wbase = wdn + (size_t)e * H_DIM * I_DIM;
    const u16* srcB[4];
    #pragma unroll
    for (int j = 0; j < 4; ++j) {
        int s = j * 256 + tid;
        int row = s >> 3, c = s & 7, cg = c ^ (row & 7);
        srcB[j] = wbase + (size_t)(nt * 128 + row) * I_DIM + cg * 8;
    }
    const u16* srcA[2];
    #pragma unroll
    for (int j = 0; j < 2; ++j) {
        int s = j * 256 + tid;
        int row = s >> 3, c = s & 7, cg = c ^ (row & 7);
        int p = ptok[row];
        srcA[j] = (p >= 0) ? hq + (size_t)p * I_DIM + cg * 8 : zbuf;
    }

    int idxA[2][2], idxB[4][2];
    #pragma unroll
    for (int fm = 0; fm < 2; ++fm) {
        int ar = m * 32 + fm * 16 + l15;
        #pragma unroll
        for (int kg = 0; kg < 2; ++kg)
            idxA[fm][kg] = 8192 + ar * 64 + (((kg * 4 + l4) ^ (ar & 7)) * 8);
    }
    #pragma unroll
    for (int nf = 0; nf < 4; ++nf) {
        int br = q * 64 + nf * 16 + l15;
        #pragma unroll
        for (int kg = 0; kg < 2; ++kg)
            idxB[nf][kg] = br * 64 + (((kg * 4 + l4) ^ (br & 7)) * 8);
    }

    auto stage = [&](int buf) {
        #pragma unroll
        for (int j = 0; j < 4; ++j) { GLDS(srcB[j], &sm[buf][j * 2048 + tid * 8]); srcB[j] += 64; }
        #pragma unroll
        for (int j = 0; j < 2; ++j) { GLDS(srcA[j], &sm[buf][8192 + j * 2048 + tid * 8]); srcA[j] += 64; }
    };

    f4v master[2][4], part[2][4];
    #pragma unroll
    for (int a = 0; a < 2; ++a)
        #pragma unroll
        for (int b = 0; b < 4; ++b) { master[a][b] = (f4v){0,0,0,0}; part[a][b] = (f4v){0,0,0,0}; }

    const float* swp = sdn + (e * 8 + nt) * 4;

    stage(0);
    __syncthreads();

    for (int t = 0; t < 8; ++t) {
        if (t < 7) stage((t + 1) & 1);
        const u16* buf = &sm[t & 1][0];
        #pragma unroll
        for (int kg = 0; kg < 2; ++kg) {
            s8v a0 = *(const s8v*)&buf[idxA[0][kg]];
            s8v a1 = *(const s8v*)&buf[idxA[1][kg]];
            #pragma unroll
            for (int nf = 0; nf < 4; ++nf) {
                s8v b = *(const s8v*)&buf[idxB[nf][kg]];
                part[0][nf] = __builtin_amdgcn_mfma_f32_16x16x32_bf16(a0, b, part[0][nf], 0, 0, 0);
                part[1][nf] = __builtin_amdgcn_mfma_f32_16x16x32_bf16(a1, b, part[1][nf], 0, 0, 0);
            }
        }
        if (t & 1) {
            int kb = t >> 1;
            float sw = swp[kb];
            #pragma unroll
            for (int fm = 0; fm < 2; ++fm) {
                float c0 = hs_l[m * 32 + fm * 16 + l4 * 4 + 0][kb] * sw;
                float c1 = hs_l[m * 32 + fm * 16 + l4 * 4 + 1][kb] * sw;
                float c2 = hs_l[m * 32 + fm * 16 + l4 * 4 + 2][kb] * sw;
                float c3 = hs_l[m * 32 + fm * 16 + l4 * 4 + 3][kb] * sw;
                #pragma unroll
                for (int nf = 0; nf < 4; ++nf) {
                    master[fm][nf][0] += c0 * part[fm][nf][0];
                    master[fm][nf][1] += c1 * part[fm][nf][1];
                    master[fm][nf][2] += c2 * part[fm][nf][2];
                    master[fm][nf][3] += c3 * part[fm][nf][3];
                    part[fm][nf] = (f4v){0,0,0,0};
                }
            }
        }
        __syncthreads();
    }

    #pragma unroll
    for (int fm = 0; fm < 2; ++fm)
        #pragma unroll
        for (int r = 0; r < 4; ++r) {
            int row = m * 32 + fm * 16 + l4 * 4 + r;
            int p = ptok[row];
            if (p < 0) continue;
            float rw = rw_l[row];
            float* drow = dout + (size_t)p * H_DIM + nt * 128 + q * 64;
            #pragma unroll
            for (int nf = 0; nf < 4; ++nf)
                drow[nf * 16 + l15] = rw * master[fm][nf][r];
        }
}

// ---------- K6: sum the 4 slot-partials per token ----------
__global__ void k_reduce(const float* __restrict__ dout, float* __restrict__ out) {
    int i = blockIdx.x * 256 + threadIdx.x;   // f32x4 index over T*H
    int t = i >> 8, h4 = i & 255;
    const float4* d = (const float4*)dout;
    float4 a = d[(size_t)(t * 4 + 0) * 256 + h4];
    float4 b = d[(size_t)(t * 4 + 1) * 256 + h4];
    float4 c = d[(size_t)(t * 4 + 2) * 256 + h4];
    float4 e = d[(size_t)(t * 4 + 3) * 256 + h4];
    float4 r;
    r.x = a.x + b.x + c.x + e.x;
    r.y = a.y + b.y + c.y + e.y;
    r.z = a.z + b.z + c.z + e.z;
    r.w = a.w + b.w + c.w + e.w;
    ((float4*)out)[i] = r;
}

extern "C" void kernel_launch(void* const* d_in, const int* in_sizes, int n_in,
                              void* d_out, int out_size, void* d_ws, size_t ws_size,
                              hipStream_t stream) {
    const float* hs_in = (const float*)d_in[0];
    const int*   tki = (const int*)d_in[1];
    const float* tkw = (const float*)d_in[2];
    const float* wgu = (const float*)d_in[3];
    const float* sgu = (const float*)d_in[4];
    const float* wdn = (const float*)d_in[5];
    const float* sdn = (const float*)d_in[6];
    float* out = (float*)d_out;

    char* ws = (char*)d_ws;
    const size_t MB = 1024 * 1024;
    u16*   wgu_bf = (u16*)(ws);                    // 32 MB; ALIASED by dout after k_gateup
    float* dout   = (float*)(ws);                  // 32 MB (NPAIR*H f32)
    u16*   wdn_bf = (u16*)(ws + 32 * MB);          // 16 MB
    u16*   xq     = (u16*)(ws + 48 * MB);          // 4 MB
    float* xs     = (float*)(ws + 52 * MB);        // 64 KB
    float* hbuf   = (float*)(ws + 53 * MB);        // 16 MB (NPAIR*I f32)
    u16*   hq     = (u16*)(ws + 69 * MB);          // 8 MB
    float* hs     = (float*)(ws + 77 * MB);        // 128 KB
    int*   counts = (int*)(ws + 78 * MB);          // 64 ints
    u16*   zbuf   = (u16*)(ws + 78 * MB + 4096);   // 4 KB zeros
    int*   lists  = (int*)(ws + 78 * MB + 65536);  // 512 KB

    hipMemsetAsync(counts, 0, 256, stream);
    hipMemsetAsync(zbuf, 0, 4096, stream);

    k_cvt<<<8192, 256, 0, stream>>>(wgu, wgu_bf, N_EXP * 2 * I_DIM * H_DIM / 8);
    k_cvt<<<4096, 256, 0, stream>>>(wdn, wdn_bf, N_EXP * H_DIM * I_DIM / 8);
    k_quant_x<<<T_TOK, 256, 0, stream>>>(hs_in, xq, xs);
    k_route<<<NPAIR / 256, 256, 0, stream>>>(tki, counts, lists);
    k_gateup<<<2048, 256, 0, stream>>>(xq, xs, counts, lists, wgu_bf, sgu, zbuf, hbuf);
    k_quant_h<<<NPAIR, 128, 0, stream>>>(hbuf, hq, hs);
    k_down<<<2048, 256, 0, stream>>>(hq, hs, counts, lists, wdn_bf, sdn, tkw, zbuf, dout);
    k_reduce<<<T_TOK * H_DIM / 1024, 256, 0, stream>>>(dout, out);
}